// Round 3
// baseline (2156.603 us; speedup 1.0000x reference)
//
#include <hip/hip_runtime.h>
#include <hip/hip_fp16.h>

typedef _Float16 half8 __attribute__((ext_vector_type(8)));
typedef float floatx4 __attribute__((ext_vector_type(4)));

#define PLANE 65536              // 16*16*256 fp16 elems per image
#define PK_ELEMS 589824          // 9*8*16*64*8 per layer

// DPP rotate-reduce: sum across the 16 lanes of a DPP row (VALU-speed, no LDS pipe)
__device__ __forceinline__ float rowsum16(float x) {
    int v;
    v = __builtin_amdgcn_update_dpp(0, __float_as_int(x), 0x121, 0xf, 0xf, false); // row_ror:1
    x += __int_as_float(v);
    v = __builtin_amdgcn_update_dpp(0, __float_as_int(x), 0x122, 0xf, 0xf, false); // row_ror:2
    x += __int_as_float(v);
    v = __builtin_amdgcn_update_dpp(0, __float_as_int(x), 0x124, 0xf, 0xf, false); // row_ror:4
    x += __int_as_float(v);
    v = __builtin_amdgcn_update_dpp(0, __float_as_int(x), 0x128, 0xf, 0xf, false); // row_ror:8
    x += __int_as_float(v);
    return x;
}

// ---------------- weight repack: fp32 -> fp16 MFMA B-fragment layout ----------------
__global__ void repack_kernel(const float* __restrict__ w2, const float* __restrict__ w3,
                              const float* __restrict__ w4, const float* __restrict__ wt,
                              _Float16* __restrict__ pk) {
    int t = blockIdx.x * 256 + threadIdx.x;     // 294912 total
    int l = t & 63;
    int idx = t >> 6;
    int nt = idx & 15; idx >>= 4;
    int ks = idx & 7;  idx >>= 3;               // idx in [0,36)
    int tap = idx % 9;
    int layer = idx / 9;
    int co = nt * 16 + (l & 15);
    int ci0 = ks * 32 + (l >> 4) * 8;
    const float* w = (layer == 0) ? w2 : (layer == 1) ? w3 : (layer == 2) ? w4 : wt;
    _Float16* dst = pk + (size_t)layer * PK_ELEMS + (((size_t)(tap * 8 + ks) * 16 + nt) * 64 + l) * 8;
    if (layer < 3) {
        for (int j = 0; j < 8; ++j)
            dst[j] = (_Float16)w[(co * 256 + (ci0 + j)) * 9 + tap];
    } else {
        int ky = tap / 3, kx = tap % 3;
        for (int j = 0; j < 8; ++j)
            dst[j] = (_Float16)w[((ci0 + j) * 256 + co) * 9 + (2 - ky) * 3 + (2 - kx)];
    }
}

// ---------------- conv1: 3->256, direct fp32, writes padded swizzled fp16 act ----------------
__global__ __launch_bounds__(1024, 4) void conv1_kernel(const float* __restrict__ x,
                                                        const float* __restrict__ w1,
                                                        const float* __restrict__ b1,
                                                        _Float16* __restrict__ act) {
    __shared__ float inl[3][16][16];
    __shared__ float lw[256 * 27];
    int n = blockIdx.x, tid = threadIdx.x;
    if (tid < 768) ((float*)inl)[tid] = 0.f;
    __syncthreads();
    for (int i = tid; i < 3 * 196; i += 1024) {
        int ci = i / 196, r = i % 196, y = r / 14, xx = r % 14;
        inl[ci][y + 1][xx + 1] = x[(size_t)n * 588 + i];
    }
    for (int i = tid; i < 256 * 27; i += 1024) lw[i] = w1[i];
    __syncthreads();
    int p = tid >> 2, q = tid & 3;
    int py = p >> 4, px = p & 15;
    _Float16* ga = act + (size_t)n * PLANE + p * 256;
    int sw = (p & 7) << 3;
    if (py == 0 || py == 15 || px == 0 || px == 15) {
        for (int co = q * 64; co < q * 64 + 64; ++co) ga[co ^ sw] = (_Float16)0.f;
    } else {
        float vin[27];
        #pragma unroll
        for (int ci = 0; ci < 3; ++ci)
            #pragma unroll
            for (int ky = 0; ky < 3; ++ky)
                #pragma unroll
                for (int kx = 0; kx < 3; ++kx)
                    vin[ci * 9 + ky * 3 + kx] = inl[ci][py - 1 + ky][px - 1 + kx];
        for (int co = q * 64; co < q * 64 + 64; ++co) {
            float acc = b1[co];
            const float* wp = &lw[co * 27];
            #pragma unroll
            for (int k = 0; k < 27; ++k) acc += vin[k] * wp[k];
            ga[co ^ sw] = (_Float16)fmaxf(acc, 0.f);
        }
    }
}

// ---------------- fused: conv2+conv3+conv4 (MFMA, LDS-resident) + convT + 1x1 + sigmoid ----------------
__global__ __launch_bounds__(1024, 4) void fused_kernel(const _Float16* __restrict__ act,
                                                        const _Float16* __restrict__ pk,
                                                        const float* __restrict__ b2,
                                                        const float* __restrict__ b3,
                                                        const float* __restrict__ b4,
                                                        const float* __restrict__ bt,
                                                        const float* __restrict__ w5,
                                                        const float* __restrict__ b5,
                                                        float* __restrict__ out) {
    __shared__ _Float16 plane[PLANE];   // 128 KB, resident across all layers
    __shared__ float o3[2352];          // [pix][c] 1x1-conv accumulator
    int n = blockIdx.x, tid = threadIdx.x;
    const _Float16* ga = act + (size_t)n * PLANE;
    #pragma unroll
    for (int i = 0; i < 8; ++i)
        *(uint4*)(plane + (i * 1024 + tid) * 8) = *(const uint4*)(ga + (i * 1024 + tid) * 8);
    for (int i = tid; i < 2352; i += 1024) o3[i] = b5[i % 3];

    int lane = tid & 63, wid = tid >> 6;
    int wm = wid >> 2, wn = wid & 3;
    int r = lane & 15, kg = lane >> 4;
    int pp[4];
    #pragma unroll
    for (int i = 0; i < 4; ++i) {
        int mt = wm + i * 4, m = mt * 16 + r;
        if (mt < 13 && m < 196) { int y = m / 14, xx = m - y * 14; pp[i] = (y + 1) * 16 + xx + 1; }
        else pp[i] = 17;
    }
    __syncthreads();

    // ---- conv2..conv4: plane -> plane, acc-in-regs is the double buffer ----
    for (int L = 0; L < 3; ++L) {
        const _Float16* pkL = pk + (size_t)L * PK_ELEMS;
        const float* bias = (L == 0) ? b2 : (L == 1) ? b3 : b4;
        float bia[4];
        #pragma unroll
        for (int ni = 0; ni < 4; ++ni) bia[ni] = bias[(wn * 4 + ni) * 16 + r];

        floatx4 acc[4][4] = {};
        for (int tap = 0; tap < 9; ++tap) {
            int dy = tap / 3 - 1, dx = tap % 3 - 1;
            int ip[4];
            #pragma unroll
            for (int i = 0; i < 4; ++i) ip[i] = pp[i] + dy * 16 + dx;
            const _Float16* pkt = pkL + (size_t)tap * (8 * 16 * 64 * 8);
            #pragma unroll
            for (int ks = 0; ks < 8; ++ks) {
                half8 a[4], b[4];
                #pragma unroll
                for (int i = 0; i < 4; ++i) {
                    int chunk = (ks * 4 + kg) ^ (ip[i] & 7);
                    a[i] = *(const half8*)(plane + ip[i] * 256 + chunk * 8);
                }
                #pragma unroll
                for (int ni = 0; ni < 4; ++ni)
                    b[ni] = *(const half8*)(pkt + (((ks * 16) + wn * 4 + ni) * 64 + lane) * 8);
                #pragma unroll
                for (int i = 0; i < 4; ++i)
                    #pragma unroll
                    for (int ni = 0; ni < 4; ++ni)
                        acc[i][ni] = __builtin_amdgcn_mfma_f32_16x16x32_f16(a[i], b[ni], acc[i][ni], 0, 0, 0);
            }
        }
        __syncthreads();   // everyone done READING plane
        #pragma unroll
        for (int i = 0; i < 4; ++i) {
            int mt = wm + i * 4;
            if (mt >= 13) continue;
            #pragma unroll
            for (int ni = 0; ni < 4; ++ni) {
                int co = (wn * 4 + ni) * 16 + r;
                #pragma unroll
                for (int reg = 0; reg < 4; ++reg) {
                    int m = mt * 16 + kg * 4 + reg;
                    if (m >= 196) continue;
                    int y = m / 14, xx = m - y * 14;
                    int ppix = (y + 1) * 16 + xx + 1;
                    float v = fmaxf(acc[i][ni][reg] + bia[ni], 0.f);
                    plane[ppix * 256 + (co ^ ((ppix & 7) << 3))] = (_Float16)v;
                }
            }
        }
        __syncthreads();   // plane updated for next layer
    }

    // ---- convT (4 parity classes) + ReLU + 1x1 conv into o3 ----
    float bta[4], w5a[4][3];
    #pragma unroll
    for (int ni = 0; ni < 4; ++ni) {
        int co = (wn * 4 + ni) * 16 + r;
        bta[ni] = bt[co];
        #pragma unroll
        for (int c = 0; c < 3; ++c) w5a[ni][c] = w5[c * 256 + co];
    }
    const _Float16* pkT = pk + (size_t)3 * PK_ELEMS;
    const int ntaps[4] = {1, 2, 2, 4};
    const int taps[4][4] = {{4, 0, 0, 0}, {3, 5, 0, 0}, {1, 7, 0, 0}, {0, 2, 6, 8}};
    const int dys[4][4]  = {{0, 0, 0, 0}, {0, 0, 0, 0}, {0, 1, 0, 0}, {0, 0, 1, 1}};
    const int dxs[4][4]  = {{0, 0, 0, 0}, {0, 1, 0, 0}, {0, 0, 0, 0}, {0, 1, 0, 1}};

    for (int cls = 0; cls < 4; ++cls) {
        int ry = cls >> 1, rx = cls & 1;
        floatx4 acc[4][4] = {};
        for (int tt = 0; tt < ntaps[cls]; ++tt) {
            int tap = taps[cls][tt];
            int doff = dys[cls][tt] * 16 + dxs[cls][tt];
            const _Float16* pkt = pkT + (size_t)tap * (8 * 16 * 64 * 8);
            #pragma unroll
            for (int ks = 0; ks < 8; ++ks) {
                half8 a[4];
                #pragma unroll
                for (int i = 0; i < 4; ++i) {
                    int ipx = pp[i] + doff;
                    int chunk = (ks * 4 + kg) ^ (ipx & 7);
                    a[i] = *(const half8*)(plane + ipx * 256 + chunk * 8);
                }
                #pragma unroll
                for (int nh = 0; nh < 2; ++nh) {
                    half8 b[2];
                    #pragma unroll
                    for (int nj = 0; nj < 2; ++nj)
                        b[nj] = *(const half8*)(pkt + (((ks * 16) + wn * 4 + nh * 2 + nj) * 64 + lane) * 8);
                    #pragma unroll
                    for (int i = 0; i < 4; ++i)
                        #pragma unroll
                        for (int nj = 0; nj < 2; ++nj)
                            acc[i][nh * 2 + nj] = __builtin_amdgcn_mfma_f32_16x16x32_f16(a[i], b[nj], acc[i][nh * 2 + nj], 0, 0, 0);
                }
            }
        }
        // ReLU + 1x1: fold ni in regs, DPP rotate-reduce over the 16 lanes sharing a pixel,
        // single-lane LDS atomic (4-way contention across wn waves).
        #pragma unroll
        for (int i = 0; i < 4; ++i) {
            int mt = wm + i * 4;
            if (mt >= 13) continue;
            #pragma unroll
            for (int reg = 0; reg < 4; ++reg) {
                int m = mt * 16 + kg * 4 + reg;   // uniform across the 16-lane DPP row
                float pc0 = 0.f, pc1 = 0.f, pc2 = 0.f;
                #pragma unroll
                for (int ni = 0; ni < 4; ++ni) {
                    float v = fmaxf(acc[i][ni][reg] + bta[ni], 0.f);
                    pc0 += v * w5a[ni][0];
                    pc1 += v * w5a[ni][1];
                    pc2 += v * w5a[ni][2];
                }
                pc0 = rowsum16(pc0);
                pc1 = rowsum16(pc1);
                pc2 = rowsum16(pc2);
                if (r == 0 && m < 196) {
                    int y = m / 14, xx = m - y * 14;
                    int pix = (2 * y + ry) * 28 + (2 * xx + rx);
                    atomicAdd(&o3[pix * 3 + 0], pc0);
                    atomicAdd(&o3[pix * 3 + 1], pc1);
                    atomicAdd(&o3[pix * 3 + 2], pc2);
                }
            }
        }
    }
    __syncthreads();
    size_t ob = (size_t)n * 2352;
    for (int i = tid; i < 2352; i += 1024) {
        int pix = i / 3, c = i % 3;
        float v = o3[i];
        out[ob + (size_t)c * 784 + pix] = 1.f / (1.f + __expf(-v));
    }
}

extern "C" void kernel_launch(void* const* d_in, const int* in_sizes, int n_in,
                              void* d_out, int out_size, void* d_ws, size_t ws_size,
                              hipStream_t stream) {
    const float* x  = (const float*)d_in[0];
    const float* w1 = (const float*)d_in[1];
    const float* b1 = (const float*)d_in[2];
    const float* w2 = (const float*)d_in[3];
    const float* b2 = (const float*)d_in[4];
    const float* w3 = (const float*)d_in[5];
    const float* b3 = (const float*)d_in[6];
    const float* w4 = (const float*)d_in[7];
    const float* b4 = (const float*)d_in[8];
    const float* wt = (const float*)d_in[9];
    const float* bt = (const float*)d_in[10];
    const float* w5 = (const float*)d_in[11];
    const float* b5 = (const float*)d_in[12];

    size_t need = ((size_t)1024 * PLANE + 4 * (size_t)PK_ELEMS) * sizeof(_Float16);
    if (ws_size < need) return;  // workspace too small — cannot run

    _Float16* act = (_Float16*)d_ws;
    _Float16* pk  = act + (size_t)1024 * PLANE;

    repack_kernel<<<1152, 256, 0, stream>>>(w2, w3, w4, wt, pk);
    conv1_kernel<<<1024, 1024, 0, stream>>>(x, w1, b1, act);
    fused_kernel<<<1024, 1024, 0, stream>>>(act, pk, b2, b3, b4, bt, w5, b5, (float*)d_out);
}

// Round 4
// 1423.239 us; speedup vs baseline: 1.5153x; 1.5153x over previous
//
#include <hip/hip_runtime.h>
#include <hip/hip_fp16.h>

typedef _Float16 half8 __attribute__((ext_vector_type(8)));
typedef _Float16 half4 __attribute__((ext_vector_type(4)));
typedef float floatx4 __attribute__((ext_vector_type(4)));

#define PLANE 65536              // 16*16*256 fp16 elems per image
#define PK_ELEMS 589824          // 9*8*16*64*8 per layer

// ---------------- weight repack: fp32 -> fp16 MFMA A-fragment layout ----------------
// pack[layer][tap][ks][nt][lane][j] = W[co = nt*16+(lane&15)][ci = ks*32+(lane>>4)*8+j][tap]
// Used as the A operand (M=co): row = lane&15, k = (lane>>4)*8+j.  layer 3 = convT
// effective weight wt[ci][co][2-ky][2-kx].
__global__ void repack_kernel(const float* __restrict__ w2, const float* __restrict__ w3,
                              const float* __restrict__ w4, const float* __restrict__ wt,
                              _Float16* __restrict__ pk) {
    int t = blockIdx.x * 256 + threadIdx.x;     // 294912 total
    int l = t & 63;
    int idx = t >> 6;
    int nt = idx & 15; idx >>= 4;
    int ks = idx & 7;  idx >>= 3;               // idx in [0,36)
    int tap = idx % 9;
    int layer = idx / 9;
    int co = nt * 16 + (l & 15);
    int ci0 = ks * 32 + (l >> 4) * 8;
    const float* w = (layer == 0) ? w2 : (layer == 1) ? w3 : (layer == 2) ? w4 : wt;
    _Float16* dst = pk + (size_t)layer * PK_ELEMS + (((size_t)(tap * 8 + ks) * 16 + nt) * 64 + l) * 8;
    if (layer < 3) {
        for (int j = 0; j < 8; ++j)
            dst[j] = (_Float16)w[(co * 256 + (ci0 + j)) * 9 + tap];
    } else {
        int ky = tap / 3, kx = tap % 3;
        for (int j = 0; j < 8; ++j)
            dst[j] = (_Float16)w[((ci0 + j) * 256 + co) * 9 + (2 - ky) * 3 + (2 - kx)];
    }
}

// ---------------- conv1: 3->256, direct fp32, writes padded swizzled fp16 act ----------------
__global__ __launch_bounds__(1024, 4) void conv1_kernel(const float* __restrict__ x,
                                                        const float* __restrict__ w1,
                                                        const float* __restrict__ b1,
                                                        _Float16* __restrict__ act) {
    __shared__ float inl[3][16][16];
    __shared__ float lw[256 * 27];
    int n = blockIdx.x, tid = threadIdx.x;
    if (tid < 768) ((float*)inl)[tid] = 0.f;
    __syncthreads();
    for (int i = tid; i < 3 * 196; i += 1024) {
        int ci = i / 196, r = i % 196, y = r / 14, xx = r % 14;
        inl[ci][y + 1][xx + 1] = x[(size_t)n * 588 + i];
    }
    for (int i = tid; i < 256 * 27; i += 1024) lw[i] = w1[i];
    __syncthreads();
    int p = tid >> 2, q = tid & 3;
    int py = p >> 4, px = p & 15;
    _Float16* ga = act + (size_t)n * PLANE + p * 256;
    int sw = (p & 7) << 3;
    if (py == 0 || py == 15 || px == 0 || px == 15) {
        for (int co = q * 64; co < q * 64 + 64; ++co) ga[co ^ sw] = (_Float16)0.f;
    } else {
        float vin[27];
        #pragma unroll
        for (int ci = 0; ci < 3; ++ci)
            #pragma unroll
            for (int ky = 0; ky < 3; ++ky)
                #pragma unroll
                for (int kx = 0; kx < 3; ++kx)
                    vin[ci * 9 + ky * 3 + kx] = inl[ci][py - 1 + ky][px - 1 + kx];
        for (int co = q * 64; co < q * 64 + 64; ++co) {
            float acc = b1[co];
            const float* wp = &lw[co * 27];
            #pragma unroll
            for (int k = 0; k < 27; ++k) acc += vin[k] * wp[k];
            ga[co ^ sw] = (_Float16)fmaxf(acc, 0.f);
        }
    }
}

// ---------------- fused: conv2..4 + convT + 1x1 + sigmoid, LDS-resident plane ----------------
// 512 threads = 8 waves: cg = wid>>1 (co-group, 4 tiles each), pg = wid&1 (px-group, 8 tiles).
// Swapped-operand MFMA: D[row=co][col=pixel] -> lane holds 4 consecutive co at one pixel.
__global__ __launch_bounds__(512, 2) void fused_kernel(const _Float16* __restrict__ act,
                                                       const _Float16* __restrict__ pk,
                                                       const float* __restrict__ b2,
                                                       const float* __restrict__ b3,
                                                       const float* __restrict__ b4,
                                                       const float* __restrict__ bt,
                                                       const float* __restrict__ w5,
                                                       const float* __restrict__ b5,
                                                       float* __restrict__ out) {
    __shared__ _Float16 plane[PLANE];   // 128 KB, resident across all layers
    __shared__ float o3[2352];          // [pix][c] 1x1-conv accumulator
    __shared__ float w5l[768];          // w5 staged for broadcast reads
    int n = blockIdx.x, tid = threadIdx.x;
    const _Float16* ga = act + (size_t)n * PLANE;
    #pragma unroll
    for (int i = 0; i < 16; ++i)
        *(uint4*)(plane + (i * 512 + tid) * 8) = *(const uint4*)(ga + (i * 512 + tid) * 8);
    for (int i = tid; i < 2352; i += 512) o3[i] = b5[i % 3];
    for (int i = tid; i < 768; i += 512) w5l[i] = w5[i];

    int lane = tid & 63, wid = tid >> 6;
    int cg = wid >> 1, pg = wid & 1;
    int col = lane & 15, kg = lane >> 4;

    int pp[8]; bool pv[8];
    #pragma unroll
    for (int i = 0; i < 8; ++i) {
        int pt = pg + 2 * i, m = pt * 16 + col;
        if (pt < 13 && m < 196) { int y = m / 14, xx = m - y * 14; pp[i] = (y + 1) * 16 + xx + 1; pv[i] = true; }
        else { pp[i] = 17; pv[i] = false; }
    }
    __syncthreads();

    floatx4 acc[8][4];

    // accumulate one tap (tap/doff compile-time at call sites in convT; runtime tap ok for conv)
    auto accum_tap = [&](const _Float16* pkL, int tap, int doff) {
        const _Float16* pkt = pkL + (size_t)tap * 65536;
        int ip[8];
        #pragma unroll
        for (int i = 0; i < 8; ++i) ip[i] = pp[i] + doff;
        #pragma unroll
        for (int ks = 0; ks < 8; ++ks) {
            half8 a[4];
            #pragma unroll
            for (int ni = 0; ni < 4; ++ni)
                a[ni] = *(const half8*)(pkt + (((ks * 16) + cg * 4 + ni) * 64 + lane) * 8);
            #pragma unroll
            for (int ih = 0; ih < 2; ++ih) {
                half8 b[4];
                #pragma unroll
                for (int j = 0; j < 4; ++j) {
                    int ipx = ip[ih * 4 + j];
                    int chunk = (ks * 4 + kg) ^ (ipx & 7);
                    b[j] = *(const half8*)(plane + ipx * 256 + chunk * 8);
                }
                #pragma unroll
                for (int j = 0; j < 4; ++j)
                    #pragma unroll
                    for (int ni = 0; ni < 4; ++ni)
                        acc[ih * 4 + j][ni] = __builtin_amdgcn_mfma_f32_16x16x32_f16(a[ni], b[j], acc[ih * 4 + j][ni], 0, 0, 0);
            }
        }
    };

    auto init_acc = [&](const float* bias) {
        #pragma unroll
        for (int ni = 0; ni < 4; ++ni) {
            floatx4 bv;
            #pragma unroll
            for (int reg = 0; reg < 4; ++reg) bv[reg] = bias[(cg * 4 + ni) * 16 + kg * 4 + reg];
            #pragma unroll
            for (int i = 0; i < 8; ++i) acc[i][ni] = bv;
        }
    };

    // ---- conv2..conv4: plane -> plane ----
    for (int L = 0; L < 3; ++L) {
        const _Float16* pkL = pk + (size_t)L * PK_ELEMS;
        init_acc((L == 0) ? b2 : (L == 1) ? b3 : b4);
        for (int tap = 0; tap < 9; ++tap)
            accum_tap(pkL, tap, (tap / 3 - 1) * 16 + (tap % 3 - 1));
        __syncthreads();   // all reads of plane done
        #pragma unroll
        for (int i = 0; i < 8; ++i) {
            int ppix = pp[i];
            int sw = (ppix & 7) << 3;
            #pragma unroll
            for (int ni = 0; ni < 4; ++ni) {
                int co0 = (cg * 4 + ni) * 16 + kg * 4;
                half4 h;
                #pragma unroll
                for (int reg = 0; reg < 4; ++reg) h[reg] = (_Float16)fmaxf(acc[i][ni][reg], 0.f);
                if (pv[i]) *(half4*)(plane + ppix * 256 + (co0 ^ sw)) = h;
            }
        }
        __syncthreads();   // plane updated for next layer
    }

    // ---- convT (4 parity classes, bt folded into init) + ReLU + 1x1 into o3 ----
    const _Float16* pkT = pk + (size_t)3 * PK_ELEMS;
    auto epilogue = [&](int ry, int rx) {
        #pragma unroll
        for (int i = 0; i < 8; ++i) {
            float s0 = 0.f, s1 = 0.f, s2 = 0.f;
            #pragma unroll
            for (int ni = 0; ni < 4; ++ni) {
                int co0 = (cg * 4 + ni) * 16 + kg * 4;
                #pragma unroll
                for (int reg = 0; reg < 4; ++reg) {
                    float v = fmaxf(acc[i][ni][reg], 0.f);
                    s0 += v * w5l[0 * 256 + co0 + reg];
                    s1 += v * w5l[1 * 256 + co0 + reg];
                    s2 += v * w5l[2 * 256 + co0 + reg];
                }
            }
            s0 += __shfl_xor(s0, 16, 64); s0 += __shfl_xor(s0, 32, 64);
            s1 += __shfl_xor(s1, 16, 64); s1 += __shfl_xor(s1, 32, 64);
            s2 += __shfl_xor(s2, 16, 64); s2 += __shfl_xor(s2, 32, 64);
            if (lane < 16 && pv[i]) {
                int pt = pg + 2 * i, m = pt * 16 + col;
                int y = m / 14, xx = m - y * 14;
                int pix = (2 * y + ry) * 28 + (2 * xx + rx);
                atomicAdd(&o3[pix * 3 + 0], s0);
                atomicAdd(&o3[pix * 3 + 1], s1);
                atomicAdd(&o3[pix * 3 + 2], s2);
            }
        }
    };

    // class (ry=0,rx=0): tap 4
    init_acc(bt);
    accum_tap(pkT, 4, 0);
    epilogue(0, 0);
    // class (0,1): taps 3 (dx0), 5 (dx1)
    init_acc(bt);
    accum_tap(pkT, 3, 0);
    accum_tap(pkT, 5, 1);
    epilogue(0, 1);
    // class (1,0): taps 1 (dy0), 7 (dy1)
    init_acc(bt);
    accum_tap(pkT, 1, 0);
    accum_tap(pkT, 7, 16);
    epilogue(1, 0);
    // class (1,1): taps 0,2,6,8
    init_acc(bt);
    accum_tap(pkT, 0, 0);
    accum_tap(pkT, 2, 1);
    accum_tap(pkT, 6, 16);
    accum_tap(pkT, 8, 17);
    epilogue(1, 1);

    __syncthreads();
    size_t ob = (size_t)n * 2352;
    for (int i = tid; i < 2352; i += 512) {
        int pix = i / 3, c = i % 3;
        float v = o3[i];
        out[ob + (size_t)c * 784 + pix] = 1.f / (1.f + __expf(-v));
    }
}

extern "C" void kernel_launch(void* const* d_in, const int* in_sizes, int n_in,
                              void* d_out, int out_size, void* d_ws, size_t ws_size,
                              hipStream_t stream) {
    const float* x  = (const float*)d_in[0];
    const float* w1 = (const float*)d_in[1];
    const float* b1 = (const float*)d_in[2];
    const float* w2 = (const float*)d_in[3];
    const float* b2 = (const float*)d_in[4];
    const float* w3 = (const float*)d_in[5];
    const float* b3 = (const float*)d_in[6];
    const float* w4 = (const float*)d_in[7];
    const float* b4 = (const float*)d_in[8];
    const float* wt = (const float*)d_in[9];
    const float* bt = (const float*)d_in[10];
    const float* w5 = (const float*)d_in[11];
    const float* b5 = (const float*)d_in[12];

    size_t need = ((size_t)1024 * PLANE + 4 * (size_t)PK_ELEMS) * sizeof(_Float16);
    if (ws_size < need) return;  // workspace too small — cannot run

    _Float16* act = (_Float16*)d_ws;
    _Float16* pk  = act + (size_t)1024 * PLANE;

    repack_kernel<<<1152, 256, 0, stream>>>(w2, w3, w4, wt, pk);
    conv1_kernel<<<1024, 1024, 0, stream>>>(x, w1, b1, act);
    fused_kernel<<<1024, 512, 0, stream>>>(act, pk, b2, b3, b4, bt, w5, b5, (float*)d_out);
}

// Round 5
// 1013.194 us; speedup vs baseline: 2.1285x; 1.4047x over previous
//
#include <hip/hip_runtime.h>
#include <hip/hip_fp16.h>

typedef _Float16 half8 __attribute__((ext_vector_type(8)));
typedef _Float16 half4 __attribute__((ext_vector_type(4)));
typedef float floatx4 __attribute__((ext_vector_type(4)));

#define PLANE 65536              // 16*16*256 fp16 elems per image
#define PK_ELEMS 589824          // 9*8*16*64*8 per layer

// ---------------- weight repack: fp32 -> fp16 MFMA A-fragment layout ----------------
// pack[layer][tap][ks][nt][lane][j] = W[co = nt*16+(lane&15)][ci = ks*32+(lane>>4)*8+j][tap]
// layer 3 = convT effective weight wt[ci][co][2-ky][2-kx].
__global__ void repack_kernel(const float* __restrict__ w2, const float* __restrict__ w3,
                              const float* __restrict__ w4, const float* __restrict__ wt,
                              _Float16* __restrict__ pk) {
    int t = blockIdx.x * 256 + threadIdx.x;     // 294912 total
    int l = t & 63;
    int idx = t >> 6;
    int nt = idx & 15; idx >>= 4;
    int ks = idx & 7;  idx >>= 3;               // idx in [0,36)
    int tap = idx % 9;
    int layer = idx / 9;
    int co = nt * 16 + (l & 15);
    int ci0 = ks * 32 + (l >> 4) * 8;
    const float* w = (layer == 0) ? w2 : (layer == 1) ? w3 : (layer == 2) ? w4 : wt;
    _Float16* dst = pk + (size_t)layer * PK_ELEMS + (((size_t)(tap * 8 + ks) * 16 + nt) * 64 + l) * 8;
    if (layer < 3) {
        for (int j = 0; j < 8; ++j)
            dst[j] = (_Float16)w[(co * 256 + (ci0 + j)) * 9 + tap];
    } else {
        int ky = tap / 3, kx = tap % 3;
        for (int j = 0; j < 8; ++j)
            dst[j] = (_Float16)w[((ci0 + j) * 256 + co) * 9 + (2 - ky) * 3 + (2 - kx)];
    }
}

// ---------------- conv1: 3->256, direct fp32, writes padded swizzled fp16 act ----------------
__global__ __launch_bounds__(1024, 4) void conv1_kernel(const float* __restrict__ x,
                                                        const float* __restrict__ w1,
                                                        const float* __restrict__ b1,
                                                        _Float16* __restrict__ act) {
    __shared__ float inl[3][16][16];
    __shared__ float lw[256 * 27];
    __shared__ float lb1[256];
    int n = blockIdx.x, tid = threadIdx.x;
    if (tid < 768) ((float*)inl)[tid] = 0.f;
    __syncthreads();
    for (int i = tid; i < 3 * 196; i += 1024) {
        int ci = i / 196, r = i % 196, y = r / 14, xx = r % 14;
        inl[ci][y + 1][xx + 1] = x[(size_t)n * 588 + i];
    }
    for (int i = tid; i < 256 * 27; i += 1024) lw[i] = w1[i];
    if (tid < 256) lb1[tid] = b1[tid];
    __syncthreads();
    int p = tid >> 2, q = tid & 3;
    int py = p >> 4, px = p & 15;
    _Float16* ga = act + (size_t)n * PLANE + p * 256;
    int sw = (p & 7) << 3;
    if (py == 0 || py == 15 || px == 0 || px == 15) {
        // co = q + 4*ci mapping (same set as compute path; order irrelevant for zero-fill)
        for (int ci = 0; ci < 64; ++ci) { int co = q + ci * 4; ga[co ^ sw] = (_Float16)0.f; }
    } else {
        float vin[27];
        #pragma unroll
        for (int ci = 0; ci < 3; ++ci)
            #pragma unroll
            for (int ky = 0; ky < 3; ++ky)
                #pragma unroll
                for (int kx = 0; kx < 3; ++kx)
                    vin[ci * 9 + ky * 3 + kx] = inl[ci][py - 1 + ky][px - 1 + kx];
        // co = q + 4*ci: lanes within a wave read lw at addresses 27*q apart -> 4 distinct banks
        for (int ci = 0; ci < 64; ++ci) {
            int co = q + ci * 4;
            float acc = lb1[co];
            const float* wp = &lw[co * 27];
            #pragma unroll
            for (int k = 0; k < 27; ++k) acc += vin[k] * wp[k];
            ga[co ^ sw] = (_Float16)fmaxf(acc, 0.f);
        }
    }
}

// ---------------- fused: conv2..4 + convT + 1x1 + sigmoid, LDS-resident plane ----------------
// 512 threads = 8 waves: cg = wid>>1 (co-group of 4 nt), pg = wid&1 (row-group: rows pg,pg+2,..).
// M-tile = one image row (16 cols incl pad, 14 valid). Swapped-operand MFMA:
// D[row=co][col=x] -> lane holds 4 consecutive co at one pixel.

#define INIT_ACC(BIASPTR)                                                        \
    {                                                                            \
        _Pragma("unroll")                                                        \
        for (int ni = 0; ni < 4; ++ni) {                                         \
            floatx4 bv;                                                          \
            _Pragma("unroll")                                                    \
            for (int reg = 0; reg < 4; ++reg)                                    \
                bv[reg] = (BIASPTR)[(cg * 4 + ni) * 16 + kg * 4 + reg];          \
            _Pragma("unroll")                                                    \
            for (int i = 0; i < 7; ++i) acc[i][ni] = bv;                         \
        }                                                                        \
    }

#define ACCUM_TAP(PKT, DOFF)                                                     \
    {                                                                            \
        const _Float16* pkt_ = (PKT);                                            \
        _Pragma("unroll")                                                        \
        for (int ks = 0; ks < 8; ++ks) {                                         \
            half8 a0 = *(const half8*)(pkt_ + (((ks * 16) + cg * 4 + 0) * 64 + lane) * 8); \
            half8 a1 = *(const half8*)(pkt_ + (((ks * 16) + cg * 4 + 1) * 64 + lane) * 8); \
            half8 a2 = *(const half8*)(pkt_ + (((ks * 16) + cg * 4 + 2) * 64 + lane) * 8); \
            half8 a3 = *(const half8*)(pkt_ + (((ks * 16) + cg * 4 + 3) * 64 + lane) * 8); \
            _Pragma("unroll")                                                    \
            for (int j = 0; j < 7; ++j) {                                        \
                int ipx = pp[j] + (DOFF);                                        \
                int chunk = (ks * 4 + kg) ^ (ipx & 7);                           \
                half8 bb = *(const half8*)(plane + ipx * 256 + chunk * 8);       \
                acc[j][0] = __builtin_amdgcn_mfma_f32_16x16x32_f16(a0, bb, acc[j][0], 0, 0, 0); \
                acc[j][1] = __builtin_amdgcn_mfma_f32_16x16x32_f16(a1, bb, acc[j][1], 0, 0, 0); \
                acc[j][2] = __builtin_amdgcn_mfma_f32_16x16x32_f16(a2, bb, acc[j][2], 0, 0, 0); \
                acc[j][3] = __builtin_amdgcn_mfma_f32_16x16x32_f16(a3, bb, acc[j][3], 0, 0, 0); \
            }                                                                    \
        }                                                                        \
    }

#define EPILOGUE(RY, RX)                                                         \
    {                                                                            \
        _Pragma("unroll")                                                        \
        for (int i = 0; i < 7; ++i) {                                            \
            float s0 = 0.f, s1 = 0.f, s2 = 0.f;                                  \
            _Pragma("unroll")                                                    \
            for (int ni = 0; ni < 4; ++ni) {                                     \
                int co0 = (cg * 4 + ni) * 16 + kg * 4;                           \
                _Pragma("unroll")                                                \
                for (int reg = 0; reg < 4; ++reg) {                              \
                    float v = fmaxf(acc[i][ni][reg], 0.f);                       \
                    s0 += v * w5l[co0 + reg];                                    \
                    s1 += v * w5l[256 + co0 + reg];                              \
                    s2 += v * w5l[512 + co0 + reg];                              \
                }                                                                \
            }                                                                    \
            s0 += __shfl_xor(s0, 16, 64); s0 += __shfl_xor(s0, 32, 64);          \
            s1 += __shfl_xor(s1, 16, 64); s1 += __shfl_xor(s1, 32, 64);          \
            s2 += __shfl_xor(s2, 16, 64); s2 += __shfl_xor(s2, 32, 64);          \
            if (lane < 14) {                                                     \
                int pt_ = pg + 2 * i;                                            \
                int pix = (2 * pt_ + (RY)) * 28 + 2 * lane + (RX);               \
                atomicAdd(&o3[pix * 3 + 0], s0);                                 \
                atomicAdd(&o3[pix * 3 + 1], s1);                                 \
                atomicAdd(&o3[pix * 3 + 2], s2);                                 \
            }                                                                    \
        }                                                                        \
    }

__global__ __launch_bounds__(512, 2) void fused_kernel(const _Float16* __restrict__ act,
                                                       const _Float16* __restrict__ pk,
                                                       const float* __restrict__ b2,
                                                       const float* __restrict__ b3,
                                                       const float* __restrict__ b4,
                                                       const float* __restrict__ bt,
                                                       const float* __restrict__ w5,
                                                       const float* __restrict__ b5,
                                                       float* __restrict__ out) {
    __shared__ _Float16 plane[PLANE];   // 128 KB, resident across all layers
    __shared__ float o3[2352];          // [pix][c] 1x1-conv accumulator
    __shared__ float w5l[768];          // w5 staged for broadcast reads
    int n = blockIdx.x, tid = threadIdx.x;
    const _Float16* ga = act + (size_t)n * PLANE;
    #pragma unroll
    for (int i = 0; i < 16; ++i)
        *(uint4*)(plane + (i * 512 + tid) * 8) = *(const uint4*)(ga + (i * 512 + tid) * 8);
    for (int i = tid; i < 2352; i += 512) o3[i] = b5[i % 3];
    for (int i = tid; i < 768; i += 512) w5l[i] = w5[i];

    int lane = tid & 63, wid = tid >> 6;
    int cg = wid >> 1, pg = wid & 1;
    int col = lane & 15, kg = lane >> 4;

    // M-tile = image row pt = pg + 2*i (i<7): pixel (y=pt, x=col), 14 valid cols.
    int pp[7];
    {
        int xc = (col < 14) ? col : 13;   // clamp invalid lanes to a safe in-bounds pixel
        #pragma unroll
        for (int i = 0; i < 7; ++i) pp[i] = (pg + 2 * i + 1) * 16 + xc + 1;
    }
    bool colok = (col < 14);
    __syncthreads();

    floatx4 acc[7][4];

    // ---- conv2..conv4: plane -> plane ----
    for (int L = 0; L < 3; ++L) {
        const _Float16* pkL = pk + (size_t)L * PK_ELEMS;
        const float* bias = (L == 0) ? b2 : (L == 1) ? b3 : b4;
        INIT_ACC(bias)
        for (int tap = 0; tap < 9; ++tap) {
            int doff = (tap / 3) * 16 + (tap % 3) - 17;
            ACCUM_TAP(pkL + (size_t)tap * 65536, doff)
        }
        __syncthreads();   // all reads of plane done
        #pragma unroll
        for (int i = 0; i < 7; ++i) {
            int ppix = pp[i];
            int sw = (ppix & 7) << 3;
            if (colok) {
                #pragma unroll
                for (int ni = 0; ni < 4; ++ni) {
                    int co0 = (cg * 4 + ni) * 16 + kg * 4;
                    half4 h;
                    #pragma unroll
                    for (int reg = 0; reg < 4; ++reg) h[reg] = (_Float16)fmaxf(acc[i][ni][reg], 0.f);
                    *(half4*)(plane + ppix * 256 + (co0 ^ sw)) = h;
                }
            }
        }
        __syncthreads();   // plane updated for next layer
    }

    // ---- convT (4 parity classes, bt folded into init) + ReLU + 1x1 into o3 ----
    const _Float16* pkT = pk + (size_t)3 * PK_ELEMS;
    // class (ry=0,rx=0): tap 4
    INIT_ACC(bt)
    ACCUM_TAP(pkT + 4 * 65536, 0)
    EPILOGUE(0, 0)
    // class (0,1): taps 3 (+0), 5 (+1)
    INIT_ACC(bt)
    ACCUM_TAP(pkT + 3 * 65536, 0)
    ACCUM_TAP(pkT + 5 * 65536, 1)
    EPILOGUE(0, 1)
    // class (1,0): taps 1 (+0), 7 (+16)
    INIT_ACC(bt)
    ACCUM_TAP(pkT + 1 * 65536, 0)
    ACCUM_TAP(pkT + 7 * 65536, 16)
    EPILOGUE(1, 0)
    // class (1,1): taps 0 (+0), 2 (+1), 6 (+16), 8 (+17)
    INIT_ACC(bt)
    ACCUM_TAP(pkT + 0 * 65536, 0)
    ACCUM_TAP(pkT + 2 * 65536, 1)
    ACCUM_TAP(pkT + 6 * 65536, 16)
    ACCUM_TAP(pkT + 8 * 65536, 17)
    EPILOGUE(1, 1)

    __syncthreads();
    size_t ob = (size_t)n * 2352;
    for (int i = tid; i < 2352; i += 512) {
        int pix = i / 3, c = i % 3;
        float v = o3[i];
        out[ob + (size_t)c * 784 + pix] = 1.f / (1.f + __expf(-v));
    }
}

extern "C" void kernel_launch(void* const* d_in, const int* in_sizes, int n_in,
                              void* d_out, int out_size, void* d_ws, size_t ws_size,
                              hipStream_t stream) {
    const float* x  = (const float*)d_in[0];
    const float* w1 = (const float*)d_in[1];
    const float* b1 = (const float*)d_in[2];
    const float* w2 = (const float*)d_in[3];
    const float* b2 = (const float*)d_in[4];
    const float* w3 = (const float*)d_in[5];
    const float* b3 = (const float*)d_in[6];
    const float* w4 = (const float*)d_in[7];
    const float* b4 = (const float*)d_in[8];
    const float* wt = (const float*)d_in[9];
    const float* bt = (const float*)d_in[10];
    const float* w5 = (const float*)d_in[11];
    const float* b5 = (const float*)d_in[12];

    size_t need = ((size_t)1024 * PLANE + 4 * (size_t)PK_ELEMS) * sizeof(_Float16);
    if (ws_size < need) return;  // workspace too small — cannot run

    _Float16* act = (_Float16*)d_ws;
    _Float16* pk  = act + (size_t)1024 * PLANE;

    repack_kernel<<<1152, 256, 0, stream>>>(w2, w3, w4, wt, pk);
    conv1_kernel<<<1024, 1024, 0, stream>>>(x, w1, b1, act);
    fused_kernel<<<1024, 512, 0, stream>>>(act, pk, b2, b3, b4, bt, w5, b5, (float*)d_out);
}